// Round 4
// baseline (148.245 us; speedup 1.0000x reference)
//
#include <hip/hip_runtime.h>
#include <cstddef>

#define EPS 1e-5f
static constexpr int Bn = 64, Cn = 64, Hn = 56, Wn = 56, HWn = Hn * Wn; // 3136
static constexpr int RB = 8;          // rows per band in fused k23
static constexpr int NBAND = 7;       // 56 / 8
static constexpr int SLAB = 3600;     // ushorts per cat slab: 448*8 + 16 pad (7200 B -> quad bank offsets {0,8,16,24})

typedef __attribute__((ext_vector_type(8))) short short8;
typedef __attribute__((ext_vector_type(8))) unsigned short ushort8;
typedef __attribute__((ext_vector_type(4))) unsigned short ushort4v;
typedef __attribute__((ext_vector_type(4))) float floatx4;
typedef __attribute__((ext_vector_type(16))) float floatx16;
typedef __attribute__((ext_vector_type(4))) unsigned int uintx4;
typedef __attribute__((ext_vector_type(2))) unsigned int uintx2;

__device__ __forceinline__ unsigned pack_rne(float a, float b) {
    unsigned ua = __float_as_uint(a), ub = __float_as_uint(b);
    ua = ua + 0x7fffu + ((ua >> 16) & 1u);
    ub = ub + 0x7fffu + ((ub >> 16) & 1u);
    return __builtin_amdgcn_perm(ub, ua, 0x07060302);
}
__device__ __forceinline__ unsigned pack_trunc(float a, float b) {
    return __builtin_amdgcn_perm(__float_as_uint(b), __float_as_uint(a), 0x07060302);
}
__device__ __forceinline__ uintx2 pmax2(uintx2 a, uintx2 b) {
    ushort4v r = __builtin_elementwise_max(*(ushort4v*)&a, *(ushort4v*)&b);
    return *(uintx2*)&r;
}
__device__ __forceinline__ float bf_lo(unsigned u) { return __uint_as_float(u << 16); }
__device__ __forceinline__ float bf_hi(unsigned u) { return __uint_as_float(u & 0xffff0000u); }

// Layouts (bf16):
//   node0: [b][chunk=8][px=3136][j=8]
//   cat (LDS, per 8-row band): 16 slabs of SLAB ushorts; slab = chunk*2 + plane
//     (plane 0 = avg, 1 = maxsum), element [px_local=448][j=8]

// ---------------------------------------------------------------------------
// K1: node0 = relu(bn1(conv1x1(x,w1))), 32x32x16 MFMA, NO x staging.
// B-frag (col=px, k=h*8+j) is loaded directly from global: per instruction,
// lanes 0-31 / 32-63 read two 128-B contiguous runs of one channel row.
// A = w1 rows with bn1 scale folded, k-mapping kt*16+h*8+j identical to the
// verified k3 pattern. No LDS transpose, no per-tile syncthreads.
// Wave handles 2 px-tiles of 32; block = 4 waves = 256 px.
// ---------------------------------------------------------------------------
__global__ __launch_bounds__(256, 4) void k1_conv1(
    const float* __restrict__ x, const float* __restrict__ w1,
    const float* __restrict__ bg, const float* __restrict__ bb,
    const float* __restrict__ bm, const float* __restrict__ bv,
    unsigned short* __restrict__ node0)
{
    __shared__ float scs[64], shs[64];
    const int tid = threadIdx.x;
    if (tid < 64) {
        float sc = bg[tid] * rsqrtf(bv[tid] + EPS);
        scs[tid] = sc;
        shs[tid] = bb[tid] - bm[tid] * sc;
    }
    __syncthreads();
    const int lane = tid & 63;
    const int wv   = tid >> 6;
    const int n    = lane & 31;
    const int h    = lane >> 5;

    // A-frags: w1[oc = oct*32+n][kt*16 + h*8 + 0..7] * sc[oc]
    short8 afr0[4], afr1[4];
    {
        const float s0 = scs[n], s1 = scs[32 + n];
        #pragma unroll
        for (int kt = 0; kt < 4; ++kt) {
            const float* wp0 = w1 + (size_t)n * 64 + kt * 16 + h * 8;
            floatx4 f0 = *(const floatx4*)wp0;
            floatx4 f1 = *(const floatx4*)(wp0 + 4);
            uintx4 u;
            u.x = pack_rne(f0[0] * s0, f0[1] * s0);
            u.y = pack_rne(f0[2] * s0, f0[3] * s0);
            u.z = pack_rne(f1[0] * s0, f1[1] * s0);
            u.w = pack_rne(f1[2] * s0, f1[3] * s0);
            afr0[kt] = *(short8*)&u;
            const float* wp1 = wp0 + 32 * 64;
            floatx4 g0 = *(const floatx4*)wp1;
            floatx4 g1 = *(const floatx4*)(wp1 + 4);
            uintx4 v;
            v.x = pack_rne(g0[0] * s1, g0[1] * s1);
            v.y = pack_rne(g0[2] * s1, g0[3] * s1);
            v.z = pack_rne(g1[0] * s1, g1[1] * s1);
            v.w = pack_rne(g1[2] * s1, g1[3] * s1);
            afr1[kt] = *(short8*)&v;
        }
    }

    #pragma unroll
    for (int s = 0; s < 2; ++s) {
        const int P = blockIdx.x * 256 + (wv * 2 + s) * 32;   // 32 | 3136: tile in one image
        const int b = P / HWn, p0 = P - b * HWn;
        const float* xb = x + (size_t)b * 64 * HWn + p0 + n;

        // B: 32 strided dword loads (each = two 128-B coalesced runs per wave)
        float f[4][8];
        #pragma unroll
        for (int kt = 0; kt < 4; ++kt)
            #pragma unroll
            for (int j = 0; j < 8; ++j)
                f[kt][j] = xb[(size_t)(kt * 16 + h * 8 + j) * HWn];

        floatx16 acc0, acc1;
        #pragma unroll
        for (int i = 0; i < 16; ++i) { acc0[i] = 0.f; acc1[i] = 0.f; }

        #pragma unroll
        for (int kt = 0; kt < 4; ++kt) {
            uintx4 u;
            u.x = pack_trunc(f[kt][0], f[kt][1]);
            u.y = pack_trunc(f[kt][2], f[kt][3]);
            u.z = pack_trunc(f[kt][4], f[kt][5]);
            u.w = pack_trunc(f[kt][6], f[kt][7]);
            short8 bfr = *(short8*)&u;
            acc0 = __builtin_amdgcn_mfma_f32_32x32x16_bf16(afr0[kt], bfr, acc0, 0, 0, 0);
            acc1 = __builtin_amdgcn_mfma_f32_32x32x16_bf16(afr1[kt], bfr, acc1, 0, 0, 0);
        }

        // epilogue: oc = oct*32 + g*8 + h*4 + i, value acc[g*4+i];
        // chunk = oct*4 + g, j = h*4 + i -> wave store = contiguous 512 B
        #pragma unroll
        for (int oct = 0; oct < 2; ++oct) {
            #pragma unroll
            for (int g = 0; g < 4; ++g) {
                floatx4 sh4 = *(const floatx4*)&shs[oct * 32 + g * 8 + h * 4];
                float v0 = (oct ? acc1[g * 4 + 0] : acc0[g * 4 + 0]) + sh4[0]; v0 = v0 > 0.f ? v0 : 0.f;
                float v1 = (oct ? acc1[g * 4 + 1] : acc0[g * 4 + 1]) + sh4[1]; v1 = v1 > 0.f ? v1 : 0.f;
                float v2 = (oct ? acc1[g * 4 + 2] : acc0[g * 4 + 2]) + sh4[2]; v2 = v2 > 0.f ? v2 : 0.f;
                float v3 = (oct ? acc1[g * 4 + 3] : acc0[g * 4 + 3]) + sh4[3]; v3 = v3 > 0.f ? v3 : 0.f;
                uintx2 st;
                st.x = pack_rne(v0, v1);
                st.y = pack_rne(v2, v3);
                const int chunk = oct * 4 + g;
                *(uintx2*)(node0 + ((size_t)(b * 8 + chunk) * HWn + p0 + n) * 8 + h * 4) = st;
            }
        }
    }
}

// ---------------------------------------------------------------------------
// K23: fused pools + conv2. Block = (b, 8-row band), 1024 thr = 16 waves.
// Unchanged from round 3.
// ---------------------------------------------------------------------------
__global__ __launch_bounds__(1024, 4) void k23_fused(
    const unsigned short* __restrict__ node0,
    const float* __restrict__ w2,
    const float* __restrict__ bg, const float* __restrict__ bb,
    const float* __restrict__ bm, const float* __restrict__ bv,
    float* __restrict__ out)
{
    __shared__ __align__(16) unsigned short catl[16 * SLAB];  // 115.2 KB
    const int tid = threadIdx.x;
    const int lane = tid & 63;
    const int wv = tid >> 6;            // 0..15

    // XCD-aware bijective swizzle (448 = 8*56): each XCD keeps 8 images
    // together so band-halo re-reads of node0 are L2 hits.
    const int bid = blockIdx.x;
    const int xcd = bid & 7;
    const int jj = bid >> 3;            // 0..55
    const int b = xcd * 8 + jj / NBAND;
    const int band = jj % NBAND;
    const int lo = band * RB;

    // ---- Phase 1: pool (chunk, col-half) into catl ----
    {
        const int chunk = wv >> 1;
        const int c0 = (wv & 1) * 28;
        const int local = lane >> 1;        // 0..31; computed cols = locals 2..29
        const int col = c0 - 2 + local;
        const int jh = lane & 1;            // 4-channel half
        const unsigned short* base = node0 + ((size_t)(b * 8 + chunk) * HWn) * 8 + jh * 4;

        const uintx2 zz = (uintx2){0u, 0u};
        auto loadrow = [&](int r) -> uintx2 {
            if (((unsigned)col >= (unsigned)Wn) | ((unsigned)r >= (unsigned)Hn)) return zz;
            return *(const uintx2*)(base + (size_t)(r * Wn + col) * 8);
        };

        float hs1[4], hs2[4];
        #pragma unroll
        for (int c = 0; c < 4; ++c) hs1[c] = hs2[c] = 0.f;
        uintx2 h5a = zz, h5b = zz, h5c = zz, h5d = zz, nh1 = zz, nh2 = zz;

        uintx2 cur = loadrow(lo - 2);
        uintx2 nxt = loadrow(lo - 1);

        unsigned short* cav = catl + (size_t)(chunk * 2) * SLAB + jh * 4;
        unsigned short* cmx = cav + SLAB;
        const bool stcol = (local >= 2) & (local <= 29);

        #pragma unroll
        for (int i = 0; i < RB + 4; ++i) {
            const int r = lo - 2 + i;
            uintx2 nx2 = (i < RB + 2) ? loadrow(r + 2) : zz;   // 2-deep prefetch

            // column taps via even-delta shuffles (jh parity preserved)
            uintx2 D0, D1, D3, D4;
            #pragma unroll
            for (int w = 0; w < 2; ++w) {
                unsigned u = cur[w];
                D1[w] = __shfl_up(u, 2);
                D0[w] = __shfl_up(u, 4);
                D3[w] = __shfl_down(u, 2);
                D4[w] = __shfl_down(u, 4);
            }

            uintx2 hm5 = pmax2(pmax2(pmax2(D0, D1), pmax2(cur, D3)), D4);
            uintx2 m5 = pmax2(pmax2(pmax2(h5a, h5b), pmax2(h5c, h5d)), hm5);
            h5a = h5b; h5b = h5c; h5c = h5d; h5d = hm5;

            float a2[4];
            #pragma unroll
            for (int w = 0; w < 2; ++w) {
                float s0 = bf_lo(D1[w]) + bf_lo(cur[w]) + bf_lo(D3[w]);
                float s1 = bf_hi(D1[w]) + bf_hi(cur[w]) + bf_hi(D3[w]);
                a2[w * 2 + 0] = (hs2[w * 2 + 0] + hs1[w * 2 + 0] + s0) * (1.f / 9.f);
                a2[w * 2 + 1] = (hs2[w * 2 + 1] + hs1[w * 2 + 1] + s1) * (1.f / 9.f);
                hs2[w * 2 + 0] = hs1[w * 2 + 0]; hs1[w * 2 + 0] = s0;
                hs2[w * 2 + 1] = hs1[w * 2 + 1]; hs1[w * 2 + 1] = s1;
            }
            uintx2 ap;
            ap.x = pack_rne(a2[0], a2[1]);
            ap.y = pack_rne(a2[2], a2[3]);

            uintx2 al, ar;
            #pragma unroll
            for (int w = 0; w < 2; ++w) {
                al[w] = __shfl_up(ap[w], 2);
                ar[w] = __shfl_down(ap[w], 2);
            }
            uintx2 nh = pmax2(pmax2(al, ap), ar);
            uintx2 m3 = pmax2(pmax2(nh2, nh1), nh);
            nh2 = nh1; nh1 = nh;

            const int r2 = r - 1, r3 = r - 2;
            if (stcol && i >= 3 && i <= RB + 2)
                *(uintx2*)(cav + (size_t)((r2 - lo) * Wn + col) * 8) = ap;
            if (stcol && i >= 4) {
                uintx2 st;
                st.x = pack_rne(bf_lo(m5.x) + bf_lo(m3.x), bf_hi(m5.x) + bf_hi(m3.x));
                st.y = pack_rne(bf_lo(m5.y) + bf_lo(m3.y), bf_hi(m5.y) + bf_hi(m3.y));
                *(uintx2*)(cmx + (size_t)((r3 - lo) * Wn + col) * 8) = st;
            }
            cur = nxt; nxt = nx2;
        }
    }

    // ---- A-frags (w2 in k-slot layout) + bn2 constants: loads issue here,
    //      latency hides under the barrier wait ----
    const int m16 = lane & 15;
    const int q = lane >> 4;
    const int t = wv & 3;
    const int e = wv >> 2;
    short8 afr[4];
    #pragma unroll
    for (int cp = 0; cp < 4; ++cp) {
        const int c = 2 * cp + (q >> 1);
        const int chb = ((q & 1) ? 64 : 0) + 8 * c;   // k-slot -> cat channel base
        const float* wp = w2 + (size_t)(t * 16 + m16) * 128 + chb;
        floatx4 f0 = *(const floatx4*)wp;
        floatx4 f1 = *(const floatx4*)(wp + 4);
        uintx4 u;
        u.x = pack_rne(f0[0], f0[1]);
        u.y = pack_rne(f0[2], f0[3]);
        u.z = pack_rne(f1[0], f1[1]);
        u.w = pack_rne(f1[2], f1[3]);
        afr[cp] = *(short8*)&u;
    }
    const int oc0 = t * 16 + q * 4;     // this lane's 4 output channels
    floatx4 g4 = *(const floatx4*)(bg + oc0);
    floatx4 bb4 = *(const floatx4*)(bb + oc0);
    floatx4 mm4 = *(const floatx4*)(bm + oc0);
    floatx4 vv4 = *(const floatx4*)(bv + oc0);
    float sc[4], sh[4];
    #pragma unroll
    for (int r = 0; r < 4; ++r) {
        sc[r] = g4[r] * rsqrtf(vv4[r] + EPS);
        sh[r] = bb4[r] - mm4[r] * sc[r];
    }
    __syncthreads();

    // ---- Phase 2: MFMA. Wave = (t = wv&3, px-quarter e = wv>>2), 7 tiles ----
    floatx4 acc[7];
    #pragma unroll
    for (int i = 0; i < 7; ++i) acc[i] = (floatx4){0.f, 0.f, 0.f, 0.f};

    #pragma unroll
    for (int cp = 0; cp < 4; ++cp) {
        #pragma unroll
        for (int i = 0; i < 7; ++i) {
            const int px = (e * 7 + i) * 16 + m16;
            // slab = 4*cp + q: quads land at bank offsets {0,8,16,24}
            short8 bfr = *(const short8*)(catl + (size_t)(4 * cp + q) * SLAB + (size_t)px * 8);
            acc[i] = __builtin_amdgcn_mfma_f32_16x16x32_bf16(afr[cp], bfr, acc[i], 0, 0, 0);
        }
    }

    // ---- epilogue: bn2 + relu + fp32 store ----
    float* ob = out + (size_t)(b * 64 + oc0) * HWn + lo * Wn;
    #pragma unroll
    for (int i = 0; i < 7; ++i) {
        const int px = (e * 7 + i) * 16 + m16;
        #pragma unroll
        for (int r = 0; r < 4; ++r) {
            float v = fmaf(acc[i][r], sc[r], sh[r]);
            ob[(size_t)r * HWn + px] = v > 0.f ? v : 0.f;
        }
    }
}

extern "C" void kernel_launch(void* const* d_in, const int* in_sizes, int n_in,
                              void* d_out, int out_size, void* d_ws, size_t ws_size,
                              hipStream_t stream)
{
    const float* x   = (const float*)d_in[0];
    const float* w1  = (const float*)d_in[1];
    const float* w2  = (const float*)d_in[2];
    const float* b1g = (const float*)d_in[3];
    const float* b1b = (const float*)d_in[4];
    const float* b1m = (const float*)d_in[5];
    const float* b1v = (const float*)d_in[6];
    const float* b2g = (const float*)d_in[7];
    const float* b2b = (const float*)d_in[8];
    const float* b2m = (const float*)d_in[9];
    const float* b2v = (const float*)d_in[10];

    float* out = (float*)d_out;
    unsigned short* node0 = (unsigned short*)d_ws;            // 25.7 MB

    k1_conv1<<<dim3(784), dim3(256), 0, stream>>>(x, w1, b1g, b1b, b1m, b1v, node0);
    k23_fused<<<dim3(Bn * NBAND), dim3(1024), 0, stream>>>(node0, w2, b2g, b2b, b2m, b2v, out);
}